// Round 1
// baseline (319.370 us; speedup 1.0000x reference)
//
#include <hip/hip_runtime.h>

// StationLoss: B=16, H=W=2048, S=5000, KERNEL_SIZE=3, METRIC=MSE
// One thread per station: gather 3x3 window (bounds-masked), window mean,
// squared error vs runoff, pre-scaled by 1/(B*S), wave-reduced, atomicAdd.

#define BB 16
#define HH 2048
#define WW 2048
#define SS 5000
#define NSTATIONS (BB * SS)

__global__ __launch_bounds__(256) void station_loss_kernel(
    const float* __restrict__ pred,       // (B,1,H,W)
    const int2*  __restrict__ pos,        // (B,S,2) -> int2 {px, py}
    const float* __restrict__ runoff,     // (B,S)
    float* __restrict__ out)              // scalar, pre-zeroed
{
    int t = blockIdx.x * blockDim.x + threadIdx.x;
    float contrib = 0.0f;
    if (t < NSTATIONS) {
        int b = t / SS;
        int2 p = pos[t];            // p.x = px (width idx), p.y = py (height idx)
        int px = p.x;
        int py = p.y;
        const float* img = pred + (size_t)b * (size_t)HH * (size_t)WW;

        float sum = 0.0f;
        float cnt = 0.0f;
        #pragma unroll
        for (int dy = -1; dy <= 1; ++dy) {
            int y = py + dy;
            if (y < 0 || y >= HH) continue;
            const float* row = img + (size_t)y * WW;
            #pragma unroll
            for (int dx = -1; dx <= 1; ++dx) {
                int x = px + dx;
                if (x < 0 || x >= WW) continue;
                sum += row[x];
                cnt += 1.0f;
            }
        }
        float avg = sum / cnt;      // cnt >= 4 always
        float d = avg - runoff[t];
        contrib = d * d * (1.0f / (float)NSTATIONS);
    }

    // wave-64 butterfly reduction
    #pragma unroll
    for (int off = 32; off > 0; off >>= 1)
        contrib += __shfl_down(contrib, off, 64);

    if ((threadIdx.x & 63) == 0)
        atomicAdd(out, contrib);
}

extern "C" void kernel_launch(void* const* d_in, const int* in_sizes, int n_in,
                              void* d_out, int out_size, void* d_ws, size_t ws_size,
                              hipStream_t stream) {
    const float* pred   = (const float*)d_in[0];
    const int2*  pos    = (const int2*)d_in[1];
    const float* runoff = (const float*)d_in[2];
    float* out = (float*)d_out;

    // d_out is poisoned 0xAA before every timed launch -> zero it (capture-safe).
    hipMemsetAsync(out, 0, sizeof(float), stream);

    const int threads = 256;
    const int blocks = (NSTATIONS + threads - 1) / threads;
    station_loss_kernel<<<blocks, threads, 0, stream>>>(pred, pos, runoff, out);
}

// Round 2
// 308.534 us; speedup vs baseline: 1.0351x; 1.0351x over previous
//
#include <hip/hip_runtime.h>

// StationLoss: B=16, H=W=2048, S=5000, KERNEL_SIZE=3, METRIC=MSE
// Kernel 1: one thread per station -> 3x3 masked window mean -> squared error,
//           block-level reduction -> partial per block in d_ws (plain store).
// Kernel 2: one block reduces the partials, writes the scalar mean to d_out
//           (plain store -- no memset / no atomics -> deterministic, no init).

#define BB 16
#define HH 2048
#define WW 2048
#define SS 5000
#define NSTATIONS (BB * SS)
#define THREADS 256
#define NBLOCKS ((NSTATIONS + THREADS - 1) / THREADS)   // 313

__global__ __launch_bounds__(THREADS) void station_partial_kernel(
    const float* __restrict__ pred,       // (B,1,H,W)
    const int2*  __restrict__ pos,        // (B,S,2) -> {px, py}
    const float* __restrict__ runoff,     // (B,S)
    float* __restrict__ partials)         // (NBLOCKS,)
{
    int t = blockIdx.x * blockDim.x + threadIdx.x;
    float contrib = 0.0f;
    if (t < NSTATIONS) {
        int b = t / SS;
        int2 p = pos[t];                  // p.x = px (width), p.y = py (height)
        int px = p.x;
        int py = p.y;
        const float* img = pred + (size_t)b * (size_t)(HH * WW);

        float sum = 0.0f;
        float cnt = 0.0f;
        #pragma unroll
        for (int dy = -1; dy <= 1; ++dy) {
            int y = py + dy;
            bool yok = (y >= 0) & (y < HH);
            int yc = min(max(y, 0), HH - 1);
            const float* row = img + (size_t)yc * WW;
            #pragma unroll
            for (int dx = -1; dx <= 1; ++dx) {
                int x = px + dx;
                bool ok = yok & (x >= 0) & (x < WW);
                int xc = min(max(x, 0), WW - 1);
                float v = row[xc];                 // always in-bounds (clamped)
                float m = ok ? 1.0f : 0.0f;
                sum += v * m;
                cnt += m;
            }
        }
        float avg = sum / cnt;            // cnt >= 4 always
        float d = avg - runoff[t];
        contrib = d * d;
    }

    // wave-64 reduction
    #pragma unroll
    for (int off = 32; off > 0; off >>= 1)
        contrib += __shfl_down(contrib, off, 64);

    __shared__ float waves[THREADS / 64];
    int lane = threadIdx.x & 63;
    int wid  = threadIdx.x >> 6;
    if (lane == 0) waves[wid] = contrib;
    __syncthreads();
    if (threadIdx.x == 0) {
        float s = 0.0f;
        #pragma unroll
        for (int i = 0; i < THREADS / 64; ++i) s += waves[i];
        partials[blockIdx.x] = s;
    }
}

__global__ __launch_bounds__(512) void reduce_kernel(
    const float* __restrict__ partials, float* __restrict__ out)
{
    float v = 0.0f;
    for (int i = threadIdx.x; i < NBLOCKS; i += 512) v += partials[i];
    #pragma unroll
    for (int off = 32; off > 0; off >>= 1)
        v += __shfl_down(v, off, 64);

    __shared__ float waves[512 / 64];
    int lane = threadIdx.x & 63;
    int wid  = threadIdx.x >> 6;
    if (lane == 0) waves[wid] = v;
    __syncthreads();
    if (threadIdx.x == 0) {
        float s = 0.0f;
        #pragma unroll
        for (int i = 0; i < 512 / 64; ++i) s += waves[i];
        out[0] = s * (1.0f / (float)NSTATIONS);
    }
}

extern "C" void kernel_launch(void* const* d_in, const int* in_sizes, int n_in,
                              void* d_out, int out_size, void* d_ws, size_t ws_size,
                              hipStream_t stream) {
    const float* pred   = (const float*)d_in[0];
    const int2*  pos    = (const int2*)d_in[1];
    const float* runoff = (const float*)d_in[2];
    float* out      = (float*)d_out;
    float* partials = (float*)d_ws;

    station_partial_kernel<<<NBLOCKS, THREADS, 0, stream>>>(pred, pos, runoff, partials);
    reduce_kernel<<<1, 512, 0, stream>>>(partials, out);
}